// Round 4
// baseline (479.514 us; speedup 1.0000x reference)
//
#include <hip/hip_runtime.h>
#include <hip/hip_bf16.h>

#define NN 100000
#define EE 1600000
#define RR 8
#define DD 64
#define MM (NN * RR)                 // 800000 (dst,rel) segments
#define BN_EPS 1e-5f
#define KTOT 576                     // 512 (rel) + 64 (root)

// bucket sort params: 256 dsts per bucket -> 2048 (dst,rel) keys per bucket
#define NB 391                       // ceil(100000/256)
#define EPB 8192                     // edges per block in binning kernels
#define NBIN ((EE + EPB - 1) / EPB)  // 196

typedef __bf16 bf16x8 __attribute__((ext_vector_type(8)));
typedef float  f32x4  __attribute__((ext_vector_type(4)));

static __device__ __forceinline__ unsigned short f32_to_bf16(float f) {
    unsigned int u = __float_as_uint(f);
    unsigned int r = u + 0x7FFFu + ((u >> 16) & 1u);   // RNE
    return (unsigned short)(r >> 16);
}
static __device__ __forceinline__ float bflo(unsigned int u) {
    return __uint_as_float(u << 16);
}
static __device__ __forceinline__ float bfhi(unsigned int u) {
    return __uint_as_float(u & 0xFFFF0000u);
}

// ---------------- bucketed CSR build ----------------

__global__ void k_bcount(const int* __restrict__ dst, int* __restrict__ btot) {
    __shared__ int cnt[NB];
    int t = threadIdx.x;
    for (int i = t; i < NB; i += 256) cnt[i] = 0;
    __syncthreads();
    int base = blockIdx.x * EPB;
#pragma unroll
    for (int i = 0; i < EPB / 256; ++i) {
        int e = base + i * 256 + t;
        if (e < EE) atomicAdd(&cnt[dst[e] >> 8], 1);
    }
    __syncthreads();
    for (int i = t; i < NB; i += 256)
        if (cnt[i]) atomicAdd(&btot[i], cnt[i]);
}

__global__ void k_bscan(const int* __restrict__ btot, int* __restrict__ bbase,
                        int* __restrict__ gcur, int* __restrict__ rowptr) {
    __shared__ int sd[512];
    int t = threadIdx.x;
    int v = (t < NB) ? btot[t] : 0;
    sd[t] = v;
    __syncthreads();
    for (int off = 1; off < 512; off <<= 1) {
        int x = (t >= off) ? sd[t - off] : 0;
        __syncthreads();
        sd[t] += x;
        __syncthreads();
    }
    if (t < NB) { bbase[t] = sd[t] - v; gcur[t] = sd[t] - v; }
    if (t == NB - 1) { bbase[NB] = sd[t]; rowptr[MM] = sd[t]; }
}

// bin edges into bucket-contiguous ebuf, packed: src | (localkey << 17)
__global__ void k_bin(const int* __restrict__ src, const int* __restrict__ dst,
                      const int* __restrict__ et, int* __restrict__ gcur,
                      unsigned int* __restrict__ ebuf) {
    __shared__ int cnt[NB];
    __shared__ int bas[NB];
    __shared__ int off[NB];
    int t = threadIdx.x;
    for (int i = t; i < NB; i += 256) { cnt[i] = 0; off[i] = 0; }
    __syncthreads();
    int base = blockIdx.x * EPB;
#pragma unroll
    for (int i = 0; i < EPB / 256; ++i) {
        int e = base + i * 256 + t;
        if (e < EE) atomicAdd(&cnt[dst[e] >> 8], 1);
    }
    __syncthreads();
    for (int i = t; i < NB; i += 256) {
        int c = cnt[i];
        bas[i] = c ? atomicAdd(&gcur[i], c) : 0;
    }
    __syncthreads();
#pragma unroll
    for (int i = 0; i < EPB / 256; ++i) {
        int e = base + i * 256 + t;
        if (e < EE) {
            int d = dst[e];
            int b = d >> 8;
            int lk = ((d & 255) << 3) | et[e];
            unsigned int rec0 = (unsigned int)src[e] | ((unsigned int)lk << 17);
            int p = bas[b] + atomicAdd(&off[b], 1);
            ebuf[p] = rec0;
        }
    }
}

// per-bucket: LDS histogram + scan -> rowptr; LDS cursors -> sorted rec
__global__ __launch_bounds__(256) void k_bcsr(const int* __restrict__ bbase,
                                              const unsigned int* __restrict__ ebuf,
                                              int* __restrict__ rowptr,
                                              int* __restrict__ rec) {
    __shared__ int deg[2048];
    __shared__ int part[256];
    int b = blockIdx.x, t = threadIdx.x;
    int e0 = bbase[b], e1 = bbase[b + 1];
    for (int i = t; i < 2048; i += 256) deg[i] = 0;
    __syncthreads();
    for (int e = e0 + t; e < e1; e += 256) atomicAdd(&deg[ebuf[e] >> 17], 1);
    __syncthreads();
    int loc[8];
    int s = 0;
#pragma unroll
    for (int j = 0; j < 8; ++j) { loc[j] = deg[t * 8 + j]; s += loc[j]; }
    part[t] = s;
    __syncthreads();
    for (int off = 1; off < 256; off <<= 1) {
        int x = (t >= off) ? part[t - off] : 0;
        __syncthreads();
        part[t] += x;
        __syncthreads();
    }
    int run = part[t] - s;
    int keyBase = b * 2048;
#pragma unroll
    for (int j = 0; j < 8; ++j) {
        int g = keyBase + t * 8 + j;
        if (g < MM) rowptr[g] = e0 + run;
        deg[t * 8 + j] = run;
        run += loc[j];
    }
    __syncthreads();
    for (int e = e0 + t; e < e1; e += 256) {
        unsigned int v = ebuf[e];
        int lk = v >> 17;
        int pos = e0 + atomicAdd(&deg[lk], 1);
        rec[pos] = (int)(v & 0x1FFFFu);
    }
}

// ---------------- fp32 -> bf16 row conversion ----------------

__global__ void k_tobf16(const float* __restrict__ X, unsigned short* __restrict__ Xb) {
    int i = blockIdx.x * 256 + threadIdx.x;
    if (i >= NN * DD / 4) return;
    float4 v = ((const float4*)X)[i];
    ushort4 o;
    o.x = f32_to_bf16(v.x); o.y = f32_to_bf16(v.y);
    o.z = f32_to_bf16(v.z); o.w = f32_to_bf16(v.w);
    ((ushort4*)Xb)[i] = o;
}

// ---------------- aggregation: wave per dst, 8 lanes per segment ----------------
// mean layout: [N][512] bf16, k = r*64 + d. Edge loop unrolled x4 so the
// rec->Xb dependent chains of consecutive edges overlap.
// (verbatim round-0 kernel: 64.7 us, ~3 TB/s, VGPR 40)

__global__ void k_agg(const unsigned short* __restrict__ Xb,
                      const int* __restrict__ rowptr,
                      const int* __restrict__ rec,
                      unsigned short* __restrict__ mean) {
    int wv = threadIdx.x >> 6;
    int lane = threadIdx.x & 63;
    int n = blockIdx.x * 4 + wv;
    if (n >= NN) return;
    int r = lane >> 3;       // segment 0..7
    int q = lane & 7;        // dim-octet 0..7
    int e0 = rowptr[n * RR + r];
    int e1 = rowptr[n * RR + r + 1];
    float a0[8] = {0,0,0,0,0,0,0,0};
    float a1[8] = {0,0,0,0,0,0,0,0};
    float a2[8] = {0,0,0,0,0,0,0,0};
    float a3[8] = {0,0,0,0,0,0,0,0};
    int e = e0;
    for (; e + 3 < e1; e += 4) {
        int s0 = rec[e], s1 = rec[e + 1], s2 = rec[e + 2], s3 = rec[e + 3];
        uint4 u0 = *(const uint4*)(Xb + (size_t)s0 * DD + q * 8);
        uint4 u1 = *(const uint4*)(Xb + (size_t)s1 * DD + q * 8);
        uint4 u2 = *(const uint4*)(Xb + (size_t)s2 * DD + q * 8);
        uint4 u3 = *(const uint4*)(Xb + (size_t)s3 * DD + q * 8);
        a0[0] += bflo(u0.x); a0[1] += bfhi(u0.x); a0[2] += bflo(u0.y); a0[3] += bfhi(u0.y);
        a0[4] += bflo(u0.z); a0[5] += bfhi(u0.z); a0[6] += bflo(u0.w); a0[7] += bfhi(u0.w);
        a1[0] += bflo(u1.x); a1[1] += bfhi(u1.x); a1[2] += bflo(u1.y); a1[3] += bfhi(u1.y);
        a1[4] += bflo(u1.z); a1[5] += bfhi(u1.z); a1[6] += bflo(u1.w); a1[7] += bfhi(u1.w);
        a2[0] += bflo(u2.x); a2[1] += bfhi(u2.x); a2[2] += bflo(u2.y); a2[3] += bfhi(u2.y);
        a2[4] += bflo(u2.z); a2[5] += bfhi(u2.z); a2[6] += bflo(u2.w); a2[7] += bfhi(u2.w);
        a3[0] += bflo(u3.x); a3[1] += bfhi(u3.x); a3[2] += bflo(u3.y); a3[3] += bfhi(u3.y);
        a3[4] += bflo(u3.z); a3[5] += bfhi(u3.z); a3[6] += bflo(u3.w); a3[7] += bfhi(u3.w);
    }
    if (e + 1 < e1) {
        int s0 = rec[e], s1 = rec[e + 1];
        uint4 u0 = *(const uint4*)(Xb + (size_t)s0 * DD + q * 8);
        uint4 u1 = *(const uint4*)(Xb + (size_t)s1 * DD + q * 8);
        a0[0] += bflo(u0.x); a0[1] += bfhi(u0.x); a0[2] += bflo(u0.y); a0[3] += bfhi(u0.y);
        a0[4] += bflo(u0.z); a0[5] += bfhi(u0.z); a0[6] += bflo(u0.w); a0[7] += bfhi(u0.w);
        a1[0] += bflo(u1.x); a1[1] += bfhi(u1.x); a1[2] += bflo(u1.y); a1[3] += bfhi(u1.y);
        a1[4] += bflo(u1.z); a1[5] += bfhi(u1.z); a1[6] += bflo(u1.w); a1[7] += bfhi(u1.w);
        e += 2;
    }
    if (e < e1) {
        int s0 = rec[e];
        uint4 u0 = *(const uint4*)(Xb + (size_t)s0 * DD + q * 8);
        a0[0] += bflo(u0.x); a0[1] += bfhi(u0.x); a0[2] += bflo(u0.y); a0[3] += bfhi(u0.y);
        a0[4] += bflo(u0.z); a0[5] += bfhi(u0.z); a0[6] += bflo(u0.w); a0[7] += bfhi(u0.w);
    }
    int cnt = e1 - e0;
    float inv = 1.0f / (float)(cnt > 1 ? cnt : 1);
    uint4 o;
    o.x = (unsigned)f32_to_bf16((a0[0]+a1[0]+a2[0]+a3[0]) * inv) | ((unsigned)f32_to_bf16((a0[1]+a1[1]+a2[1]+a3[1]) * inv) << 16);
    o.y = (unsigned)f32_to_bf16((a0[2]+a1[2]+a2[2]+a3[2]) * inv) | ((unsigned)f32_to_bf16((a0[3]+a1[3]+a2[3]+a3[3]) * inv) << 16);
    o.z = (unsigned)f32_to_bf16((a0[4]+a1[4]+a2[4]+a3[4]) * inv) | ((unsigned)f32_to_bf16((a0[5]+a1[5]+a2[5]+a3[5]) * inv) << 16);
    o.w = (unsigned)f32_to_bf16((a0[6]+a1[6]+a2[6]+a3[6]) * inv) | ((unsigned)f32_to_bf16((a0[7]+a1[7]+a2[7]+a3[7]) * inv) << 16);
    *(uint4*)(mean + (size_t)n * 512 + r * 64 + q * 8) = o;
}

// ---------------- weight prep: WcT[64][576] bf16, k = r*64+d (+root tail) ----------------

__global__ void k_prepw(const float* __restrict__ W, const float* __restrict__ Root,
                        unsigned short* __restrict__ WcT) {
    int i = blockIdx.x * 256 + threadIdx.x;
    if (i >= 64 * KTOT) return;
    int o = i / KTOT;
    int k = i - o * KTOT;
    float v;
    if (k < 512) v = W[(size_t)(k >> 6) * 4096 + (k & 63) * 64 + o];
    else         v = Root[(k - 512) * 64 + o];
    WcT[(size_t)o * KTOT + k] = f32_to_bf16(v);
}

// ---------------- MFMA GEMM: out[N][64] = [mean | Xb] @ Wc + bias ----------------
// DE-STAGED: B-fragments read directly from WcT (73 KB, resident in every
// XCD L2) -> LDS drops from 74.75 KB (2 blocks/CU, 25% occupancy) to 2 KB
// (8 blocks/CU, 100%). 64 rows per block (grid 1563): wave = one 16x64 tile.
// Optional fused column-stats (sum, sumsq) for BN.

__global__ __launch_bounds__(256) void k_gemm(const unsigned short* __restrict__ meanB,
                                              const unsigned short* __restrict__ Xb,
                                              const unsigned short* __restrict__ WcT,
                                              const float* __restrict__ bias,
                                              float* __restrict__ Out,
                                              float* __restrict__ stats,
                                              int dostats) {
    __shared__ float ssum[4][64];
    __shared__ float ssq[4][64];
    int t = threadIdx.x;
    int wv = t >> 6, lane = t & 63;
    int quad = lane >> 4, m16 = lane & 15;
    int row0 = blockIdx.x * 64 + wv * 16;
    int r0 = row0 + m16;
    bool ok0 = r0 < NN;

    union AU { uint4 u; bf16x8 f; };
    f32x4 acc[4];
#pragma unroll
    for (int j = 0; j < 4; ++j) acc[j] = (f32x4){0.f, 0.f, 0.f, 0.f};

    const unsigned short* a0p = meanB + (size_t)r0 * 512 + quad * 8;
    const unsigned short* x0p = Xb + (size_t)r0 * DD + quad * 8;
    const unsigned short* bs  = WcT + (size_t)m16 * KTOT + quad * 8;

#pragma unroll
    for (int kb = 0; kb < 16; ++kb) {
        AU av0, bv[4];
        if (ok0) av0.u = *(const uint4*)(a0p + kb * 32); else av0.u = make_uint4(0,0,0,0);
#pragma unroll
        for (int nt = 0; nt < 4; ++nt)
            bv[nt].u = *(const uint4*)(bs + (size_t)nt * 16 * KTOT + kb * 32);
#pragma unroll
        for (int nt = 0; nt < 4; ++nt)
            acc[nt] = __builtin_amdgcn_mfma_f32_16x16x32_bf16(av0.f, bv[nt].f, acc[nt], 0, 0, 0);
    }
#pragma unroll
    for (int kb = 0; kb < 2; ++kb) {
        AU av0, bv[4];
        if (ok0) av0.u = *(const uint4*)(x0p + kb * 32); else av0.u = make_uint4(0,0,0,0);
#pragma unroll
        for (int nt = 0; nt < 4; ++nt)
            bv[nt].u = *(const uint4*)(bs + (size_t)nt * 16 * KTOT + 512 + kb * 32);
#pragma unroll
        for (int nt = 0; nt < 4; ++nt)
            acc[nt] = __builtin_amdgcn_mfma_f32_16x16x32_bf16(av0.f, bv[nt].f, acc[nt], 0, 0, 0);
    }

#pragma unroll
    for (int nt = 0; nt < 4; ++nt) {
        int col = nt * 16 + m16;
        float bb = bias[col];
#pragma unroll
        for (int i = 0; i < 4; ++i) {
            int row = row0 + quad * 4 + i;
            if (row < NN) Out[(size_t)row * 64 + col] = acc[nt][i] + bb;
        }
    }

    if (dostats) {
#pragma unroll
        for (int nt = 0; nt < 4; ++nt) {
            int col = nt * 16 + m16;
            float bb = bias[col];
            float s = 0.f, sq = 0.f;
#pragma unroll
            for (int i = 0; i < 4; ++i) {
                int row = row0 + quad * 4 + i;
                if (row < NN) {
                    float v = acc[nt][i] + bb;
                    s += v; sq += v * v;
                }
            }
            s += __shfl_xor(s, 16); s += __shfl_xor(s, 32);
            sq += __shfl_xor(sq, 16); sq += __shfl_xor(sq, 32);
            if (quad == 0) { ssum[wv][col] = s; ssq[wv][col] = sq; }
        }
        __syncthreads();
        if (t < 128) {
            int col = t & 63;
            if (t < 64) {
                float s = ssum[0][col] + ssum[1][col] + ssum[2][col] + ssum[3][col];
                atomicAdd(&stats[col], s);
            } else {
                float sq = ssq[0][col] + ssq[1][col] + ssq[2][col] + ssq[3][col];
                atomicAdd(&stats[64 + col], sq);
            }
        }
    }
}

// ---------------- BN+ReLU (read fp32 H, write bf16 Hb only) ----------------

__global__ void k_bnrelu(const float* __restrict__ H, unsigned short* __restrict__ Hb,
                         const float* __restrict__ stats,
                         const float* __restrict__ gamma, const float* __restrict__ beta) {
    int idx = blockIdx.x * 256 + threadIdx.x;
    const int total = NN * DD / 4;
    if (idx >= total) return;
    int c0 = (idx & 15) * 4;
    float4 v = ((const float4*)H)[idx];
    float inv = 1.0f / (float)NN;
    float4 o;
    {
        float mu = stats[c0 + 0] * inv;
        float var = stats[64 + c0 + 0] * inv - mu * mu;
        float sc = gamma[c0 + 0] * rsqrtf(var + BN_EPS);
        float r = sc * (v.x - mu) + beta[c0 + 0];
        o.x = r > 0.f ? r : 0.f;
    }
    {
        float mu = stats[c0 + 1] * inv;
        float var = stats[64 + c0 + 1] * inv - mu * mu;
        float sc = gamma[c0 + 1] * rsqrtf(var + BN_EPS);
        float r = sc * (v.y - mu) + beta[c0 + 1];
        o.y = r > 0.f ? r : 0.f;
    }
    {
        float mu = stats[c0 + 2] * inv;
        float var = stats[64 + c0 + 2] * inv - mu * mu;
        float sc = gamma[c0 + 2] * rsqrtf(var + BN_EPS);
        float r = sc * (v.z - mu) + beta[c0 + 2];
        o.z = r > 0.f ? r : 0.f;
    }
    {
        float mu = stats[c0 + 3] * inv;
        float var = stats[64 + c0 + 3] * inv - mu * mu;
        float sc = gamma[c0 + 3] * rsqrtf(var + BN_EPS);
        float r = sc * (v.w - mu) + beta[c0 + 3];
        o.w = r > 0.f ? r : 0.f;
    }
    ushort4 ob;
    ob.x = f32_to_bf16(o.x); ob.y = f32_to_bf16(o.y);
    ob.z = f32_to_bf16(o.z); ob.w = f32_to_bf16(o.w);
    ((ushort4*)Hb)[idx] = ob;
}

// ---------------- launch ----------------

static inline size_t alignup(size_t x) { return (x + 255) & ~(size_t)255; }

extern "C" void kernel_launch(void* const* d_in, const int* in_sizes, int n_in,
                              void* d_out, int out_size, void* d_ws, size_t ws_size,
                              hipStream_t stream) {
    const float* x      = (const float*)d_in[0];
    const int*   eidx   = (const int*)d_in[1];
    const int*   etype  = (const int*)d_in[2];
    const float* w1     = (const float*)d_in[3];
    const float* root1  = (const float*)d_in[4];
    const float* b1     = (const float*)d_in[5];
    const float* gamma1 = (const float*)d_in[6];
    const float* beta1  = (const float*)d_in[7];
    const float* w2     = (const float*)d_in[8];
    const float* root2  = (const float*)d_in[9];
    const float* b2     = (const float*)d_in[10];
    float* out = (float*)d_out;

    const int* src = eidx;
    const int* dst = eidx + EE;

    char* w = (char*)d_ws;
    int* rowptr = (int*)w;            w += alignup((size_t)(MM + 1) * 4);
    int* btot   = (int*)w;            w += alignup(512 * 4);
    int* bbase  = (int*)w;            w += alignup(512 * 4);
    int* gcur   = (int*)w;            w += alignup(512 * 4);
    int* rec    = (int*)w;            w += alignup((size_t)EE * 4);
    unsigned short* mean = (unsigned short*)w; w += alignup((size_t)NN * 512 * 2);
    float* h    = (float*)w;          w += alignup((size_t)NN * DD * 4);
    unsigned short* xhb = (unsigned short*)w; w += alignup((size_t)NN * DD * 2);
    unsigned short* wct1 = (unsigned short*)w; w += alignup((size_t)64 * KTOT * 2);
    unsigned short* wct2 = (unsigned short*)w; w += alignup((size_t)64 * KTOT * 2);
    float* stats = (float*)w;         w += alignup(128 * 4);
    unsigned int* ebuf = (unsigned int*)mean;   // alias: dead before k_agg writes mean

    hipMemsetAsync(btot, 0, 512 * 4, stream);
    hipMemsetAsync(stats, 0, 128 * 4, stream);

    k_prepw<<<dim3(144), dim3(256), 0, stream>>>(w1, root1, wct1);
    k_prepw<<<dim3(144), dim3(256), 0, stream>>>(w2, root2, wct2);
    k_tobf16<<<dim3(NN * DD / 4 / 256 + 1), dim3(256), 0, stream>>>(x, xhb);

    // bucketed CSR build
    k_bcount<<<dim3(NBIN), dim3(256), 0, stream>>>(dst, btot);
    k_bscan<<<dim3(1), dim3(512), 0, stream>>>(btot, bbase, gcur, rowptr);
    k_bin<<<dim3(NBIN), dim3(256), 0, stream>>>(src, dst, etype, gcur, ebuf);
    k_bcsr<<<dim3(NB), dim3(256), 0, stream>>>(bbase, ebuf, rowptr, rec);

    // layer 1 (gemm fuses BN column stats)
    k_agg<<<dim3((NN + 3) / 4), dim3(256), 0, stream>>>(xhb, rowptr, rec, mean);
    k_gemm<<<dim3((NN + 63) / 64), dim3(256), 0, stream>>>(mean, xhb, wct1, b1, h, stats, 1);
    k_bnrelu<<<dim3(NN * DD / 4 / 256), dim3(256), 0, stream>>>(h, xhb, stats, gamma1, beta1);

    // layer 2 (xhb now holds bf16 of post-BN/ReLU h)
    k_agg<<<dim3((NN + 3) / 4), dim3(256), 0, stream>>>(xhb, rowptr, rec, mean);
    k_gemm<<<dim3((NN + 63) / 64), dim3(256), 0, stream>>>(mean, xhb, wct2, b2, out, stats, 0);
}

// Round 5
// 457.483 us; speedup vs baseline: 1.0482x; 1.0482x over previous
//
#include <hip/hip_runtime.h>
#include <hip/hip_bf16.h>

#define NN 100000
#define EE 1600000
#define RR 8
#define DD 64
#define MM (NN * RR)                 // 800000 (dst,rel) segments
#define BN_EPS 1e-5f
#define KTOT 576                     // 512 (rel) + 64 (root)

// bucket sort params: 256 dsts per bucket -> 2048 (dst,rel) keys per bucket
#define NB 391                       // ceil(100000/256)
#define EPB 8192                     // edges per block in binning kernels
#define NBIN ((EE + EPB - 1) / EPB)  // 196

typedef __bf16 bf16x8 __attribute__((ext_vector_type(8)));
typedef float  f32x4  __attribute__((ext_vector_type(4)));

static __device__ __forceinline__ unsigned short f32_to_bf16(float f) {
    unsigned int u = __float_as_uint(f);
    unsigned int r = u + 0x7FFFu + ((u >> 16) & 1u);   // RNE
    return (unsigned short)(r >> 16);
}
static __device__ __forceinline__ float bflo(unsigned int u) {
    return __uint_as_float(u << 16);
}
static __device__ __forceinline__ float bfhi(unsigned int u) {
    return __uint_as_float(u & 0xFFFF0000u);
}

// ---------------- bucketed CSR build ----------------

__global__ void k_bcount(const int* __restrict__ dst, int* __restrict__ btot) {
    __shared__ int cnt[NB];
    int t = threadIdx.x;
    for (int i = t; i < NB; i += 256) cnt[i] = 0;
    __syncthreads();
    int base = blockIdx.x * EPB;
#pragma unroll
    for (int i = 0; i < EPB / 256; ++i) {
        int e = base + i * 256 + t;
        if (e < EE) atomicAdd(&cnt[dst[e] >> 8], 1);
    }
    __syncthreads();
    for (int i = t; i < NB; i += 256)
        if (cnt[i]) atomicAdd(&btot[i], cnt[i]);
}

__global__ void k_bscan(const int* __restrict__ btot, int* __restrict__ bbase,
                        int* __restrict__ gcur, int* __restrict__ rowptr) {
    __shared__ int sd[512];
    int t = threadIdx.x;
    int v = (t < NB) ? btot[t] : 0;
    sd[t] = v;
    __syncthreads();
    for (int off = 1; off < 512; off <<= 1) {
        int x = (t >= off) ? sd[t - off] : 0;
        __syncthreads();
        sd[t] += x;
        __syncthreads();
    }
    if (t < NB) { bbase[t] = sd[t] - v; gcur[t] = sd[t] - v; }
    if (t == NB - 1) { bbase[NB] = sd[t]; rowptr[MM] = sd[t]; }
}

// bin edges into bucket-contiguous ebuf, packed: src | (localkey << 17)
__global__ void k_bin(const int* __restrict__ src, const int* __restrict__ dst,
                      const int* __restrict__ et, int* __restrict__ gcur,
                      unsigned int* __restrict__ ebuf) {
    __shared__ int cnt[NB];
    __shared__ int bas[NB];
    __shared__ int off[NB];
    int t = threadIdx.x;
    for (int i = t; i < NB; i += 256) { cnt[i] = 0; off[i] = 0; }
    __syncthreads();
    int base = blockIdx.x * EPB;
#pragma unroll
    for (int i = 0; i < EPB / 256; ++i) {
        int e = base + i * 256 + t;
        if (e < EE) atomicAdd(&cnt[dst[e] >> 8], 1);
    }
    __syncthreads();
    for (int i = t; i < NB; i += 256) {
        int c = cnt[i];
        bas[i] = c ? atomicAdd(&gcur[i], c) : 0;
    }
    __syncthreads();
#pragma unroll
    for (int i = 0; i < EPB / 256; ++i) {
        int e = base + i * 256 + t;
        if (e < EE) {
            int d = dst[e];
            int b = d >> 8;
            int lk = ((d & 255) << 3) | et[e];
            unsigned int rec0 = (unsigned int)src[e] | ((unsigned int)lk << 17);
            int p = bas[b] + atomicAdd(&off[b], 1);
            ebuf[p] = rec0;
        }
    }
}

// per-bucket: LDS histogram + scan -> rowptr; LDS cursors -> sorted rec
__global__ __launch_bounds__(256) void k_bcsr(const int* __restrict__ bbase,
                                              const unsigned int* __restrict__ ebuf,
                                              int* __restrict__ rowptr,
                                              int* __restrict__ rec) {
    __shared__ int deg[2048];
    __shared__ int part[256];
    int b = blockIdx.x, t = threadIdx.x;
    int e0 = bbase[b], e1 = bbase[b + 1];
    for (int i = t; i < 2048; i += 256) deg[i] = 0;
    __syncthreads();
    for (int e = e0 + t; e < e1; e += 256) atomicAdd(&deg[ebuf[e] >> 17], 1);
    __syncthreads();
    int loc[8];
    int s = 0;
#pragma unroll
    for (int j = 0; j < 8; ++j) { loc[j] = deg[t * 8 + j]; s += loc[j]; }
    part[t] = s;
    __syncthreads();
    for (int off = 1; off < 256; off <<= 1) {
        int x = (t >= off) ? part[t - off] : 0;
        __syncthreads();
        part[t] += x;
        __syncthreads();
    }
    int run = part[t] - s;
    int keyBase = b * 2048;
#pragma unroll
    for (int j = 0; j < 8; ++j) {
        int g = keyBase + t * 8 + j;
        if (g < MM) rowptr[g] = e0 + run;
        deg[t * 8 + j] = run;
        run += loc[j];
    }
    __syncthreads();
    for (int e = e0 + t; e < e1; e += 256) {
        unsigned int v = ebuf[e];
        int lk = v >> 17;
        int pos = e0 + atomicAdd(&deg[lk], 1);
        rec[pos] = (int)(v & 0x1FFFFu);
    }
}

// ---------------- fp32 -> bf16 row conversion ----------------

__global__ void k_tobf16(const float* __restrict__ X, unsigned short* __restrict__ Xb) {
    int i = blockIdx.x * 256 + threadIdx.x;
    if (i >= NN * DD / 4) return;
    float4 v = ((const float4*)X)[i];
    ushort4 o;
    o.x = f32_to_bf16(v.x); o.y = f32_to_bf16(v.y);
    o.z = f32_to_bf16(v.z); o.w = f32_to_bf16(v.w);
    ((ushort4*)Xb)[i] = o;
}

// ---------------- aggregation: wave per dst, 8 lanes per segment ----------------
// mean layout: [N][512] bf16, k = r*64 + d. Edge loop unrolled x4 so the
// rec->Xb dependent chains of consecutive edges overlap.
// (verbatim round-0 kernel: 64.7 us, ~3 TB/s, VGPR 40)

__global__ void k_agg(const unsigned short* __restrict__ Xb,
                      const int* __restrict__ rowptr,
                      const int* __restrict__ rec,
                      unsigned short* __restrict__ mean) {
    int wv = threadIdx.x >> 6;
    int lane = threadIdx.x & 63;
    int n = blockIdx.x * 4 + wv;
    if (n >= NN) return;
    int r = lane >> 3;       // segment 0..7
    int q = lane & 7;        // dim-octet 0..7
    int e0 = rowptr[n * RR + r];
    int e1 = rowptr[n * RR + r + 1];
    float a0[8] = {0,0,0,0,0,0,0,0};
    float a1[8] = {0,0,0,0,0,0,0,0};
    float a2[8] = {0,0,0,0,0,0,0,0};
    float a3[8] = {0,0,0,0,0,0,0,0};
    int e = e0;
    for (; e + 3 < e1; e += 4) {
        int s0 = rec[e], s1 = rec[e + 1], s2 = rec[e + 2], s3 = rec[e + 3];
        uint4 u0 = *(const uint4*)(Xb + (size_t)s0 * DD + q * 8);
        uint4 u1 = *(const uint4*)(Xb + (size_t)s1 * DD + q * 8);
        uint4 u2 = *(const uint4*)(Xb + (size_t)s2 * DD + q * 8);
        uint4 u3 = *(const uint4*)(Xb + (size_t)s3 * DD + q * 8);
        a0[0] += bflo(u0.x); a0[1] += bfhi(u0.x); a0[2] += bflo(u0.y); a0[3] += bfhi(u0.y);
        a0[4] += bflo(u0.z); a0[5] += bfhi(u0.z); a0[6] += bflo(u0.w); a0[7] += bfhi(u0.w);
        a1[0] += bflo(u1.x); a1[1] += bfhi(u1.x); a1[2] += bflo(u1.y); a1[3] += bfhi(u1.y);
        a1[4] += bflo(u1.z); a1[5] += bfhi(u1.z); a1[6] += bflo(u1.w); a1[7] += bfhi(u1.w);
        a2[0] += bflo(u2.x); a2[1] += bfhi(u2.x); a2[2] += bflo(u2.y); a2[3] += bfhi(u2.y);
        a2[4] += bflo(u2.z); a2[5] += bfhi(u2.z); a2[6] += bflo(u2.w); a2[7] += bfhi(u2.w);
        a3[0] += bflo(u3.x); a3[1] += bfhi(u3.x); a3[2] += bflo(u3.y); a3[3] += bfhi(u3.y);
        a3[4] += bflo(u3.z); a3[5] += bfhi(u3.z); a3[6] += bflo(u3.w); a3[7] += bfhi(u3.w);
    }
    if (e + 1 < e1) {
        int s0 = rec[e], s1 = rec[e + 1];
        uint4 u0 = *(const uint4*)(Xb + (size_t)s0 * DD + q * 8);
        uint4 u1 = *(const uint4*)(Xb + (size_t)s1 * DD + q * 8);
        a0[0] += bflo(u0.x); a0[1] += bfhi(u0.x); a0[2] += bflo(u0.y); a0[3] += bfhi(u0.y);
        a0[4] += bflo(u0.z); a0[5] += bfhi(u0.z); a0[6] += bflo(u0.w); a0[7] += bfhi(u0.w);
        a1[0] += bflo(u1.x); a1[1] += bfhi(u1.x); a1[2] += bflo(u1.y); a1[3] += bfhi(u1.y);
        a1[4] += bflo(u1.z); a1[5] += bfhi(u1.z); a1[6] += bflo(u1.w); a1[7] += bfhi(u1.w);
        e += 2;
    }
    if (e < e1) {
        int s0 = rec[e];
        uint4 u0 = *(const uint4*)(Xb + (size_t)s0 * DD + q * 8);
        a0[0] += bflo(u0.x); a0[1] += bfhi(u0.x); a0[2] += bflo(u0.y); a0[3] += bfhi(u0.y);
        a0[4] += bflo(u0.z); a0[5] += bfhi(u0.z); a0[6] += bflo(u0.w); a0[7] += bfhi(u0.w);
    }
    int cnt = e1 - e0;
    float inv = 1.0f / (float)(cnt > 1 ? cnt : 1);
    uint4 o;
    o.x = (unsigned)f32_to_bf16((a0[0]+a1[0]+a2[0]+a3[0]) * inv) | ((unsigned)f32_to_bf16((a0[1]+a1[1]+a2[1]+a3[1]) * inv) << 16);
    o.y = (unsigned)f32_to_bf16((a0[2]+a1[2]+a2[2]+a3[2]) * inv) | ((unsigned)f32_to_bf16((a0[3]+a1[3]+a2[3]+a3[3]) * inv) << 16);
    o.z = (unsigned)f32_to_bf16((a0[4]+a1[4]+a2[4]+a3[4]) * inv) | ((unsigned)f32_to_bf16((a0[5]+a1[5]+a2[5]+a3[5]) * inv) << 16);
    o.w = (unsigned)f32_to_bf16((a0[6]+a1[6]+a2[6]+a3[6]) * inv) | ((unsigned)f32_to_bf16((a0[7]+a1[7]+a2[7]+a3[7]) * inv) << 16);
    *(uint4*)(mean + (size_t)n * 512 + r * 64 + q * 8) = o;
}

// ---------------- weight prep: WcT[64][576] bf16, k = r*64+d (+root tail) ----------------

__global__ void k_prepw(const float* __restrict__ W, const float* __restrict__ Root,
                        unsigned short* __restrict__ WcT) {
    int i = blockIdx.x * 256 + threadIdx.x;
    if (i >= 64 * KTOT) return;
    int o = i / KTOT;
    int k = i - o * KTOT;
    float v;
    if (k < 512) v = W[(size_t)(k >> 6) * 4096 + (k & 63) * 64 + o];
    else         v = Root[(k - 512) * 64 + o];
    WcT[(size_t)o * KTOT + k] = f32_to_bf16(v);
}

// ---------------- MFMA GEMM: out[N][64] = [mean | Xb] @ Wc + bias ----------------
// Wave = 64 rows x 16 cols: each wave's ENTIRE B operand (16 cols x 576 k)
// lives in 72 VGPRs, loaded once from L2-resident WcT. The k-loop is then 18
// independent A-loads + 18 MFMAs per row-tile -> deep pipelining, no LDS,
// no syncthreads. __launch_bounds__(256,2) caps at 256 VGPRs so the
// scheduler is NOT forced into the 32-reg serialization seen in R2-R4.
// BN stats: columns disjoint per wave -> pure-register shfl + atomicAdd.

__global__ __launch_bounds__(256, 2) void k_gemm(const unsigned short* __restrict__ meanB,
                                                 const unsigned short* __restrict__ Xb,
                                                 const unsigned short* __restrict__ WcT,
                                                 const float* __restrict__ bias,
                                                 float* __restrict__ Out,
                                                 float* __restrict__ stats,
                                                 int dostats) {
    int t = threadIdx.x;
    int wv = t >> 6, lane = t & 63;
    int quad = lane >> 4, m16 = lane & 15;
    int col = wv * 16 + m16;                 // this wave's column slice
    union AU { uint4 u; bf16x8 f; };

    // B once per wave: 18 uint4 = 72 VGPRs
    AU bfrag[18];
    const unsigned short* bg = WcT + (size_t)col * KTOT + quad * 8;
#pragma unroll
    for (int kb = 0; kb < 18; ++kb)
        bfrag[kb].u = *(const uint4*)(bg + kb * 32);

    int row0 = blockIdx.x * 64;
    float bb = bias[col];
    float s = 0.f, sq = 0.f;

    f32x4 acc0 = (f32x4){0.f,0.f,0.f,0.f};
    f32x4 acc1 = (f32x4){0.f,0.f,0.f,0.f};
    f32x4 acc2 = (f32x4){0.f,0.f,0.f,0.f};
    f32x4 acc3 = (f32x4){0.f,0.f,0.f,0.f};

#pragma unroll
    for (int rt = 0; rt < 4; ++rt) {
        int r0 = row0 + rt * 16 + m16;
        bool ok = r0 < NN;
        const unsigned short* ap = meanB + (size_t)r0 * 512 + quad * 8;
        const unsigned short* xp = Xb + (size_t)r0 * DD + quad * 8;
        AU av[18];
#pragma unroll
        for (int kb = 0; kb < 16; ++kb)
            av[kb].u = ok ? *(const uint4*)(ap + kb * 32) : make_uint4(0,0,0,0);
        av[16].u = ok ? *(const uint4*)(xp) : make_uint4(0,0,0,0);
        av[17].u = ok ? *(const uint4*)(xp + 32) : make_uint4(0,0,0,0);
        f32x4 a = (f32x4){0.f,0.f,0.f,0.f};
#pragma unroll
        for (int kb = 0; kb < 18; ++kb)
            a = __builtin_amdgcn_mfma_f32_16x16x32_bf16(av[kb].f, bfrag[kb].f, a, 0, 0, 0);
        if (rt == 0) acc0 = a;
        else if (rt == 1) acc1 = a;
        else if (rt == 2) acc2 = a;
        else acc3 = a;
    }

    // epilogue: store + stats (per-lane, columns disjoint across waves)
#pragma unroll
    for (int rt = 0; rt < 4; ++rt) {
        f32x4 a = (rt == 0) ? acc0 : (rt == 1) ? acc1 : (rt == 2) ? acc2 : acc3;
#pragma unroll
        for (int i = 0; i < 4; ++i) {
            int row = row0 + rt * 16 + quad * 4 + i;
            if (row < NN) {
                float v = a[i] + bb;
                Out[(size_t)row * 64 + col] = v;
                s += v; sq += v * v;
            }
        }
    }
    if (dostats) {
        s += __shfl_xor(s, 16); s += __shfl_xor(s, 32);
        sq += __shfl_xor(sq, 16); sq += __shfl_xor(sq, 32);
        if (quad == 0) {
            atomicAdd(&stats[col], s);
            atomicAdd(&stats[64 + col], sq);
        }
    }
}

// ---------------- BN+ReLU (read fp32 H, write bf16 Hb only) ----------------

__global__ void k_bnrelu(const float* __restrict__ H, unsigned short* __restrict__ Hb,
                         const float* __restrict__ stats,
                         const float* __restrict__ gamma, const float* __restrict__ beta) {
    int idx = blockIdx.x * 256 + threadIdx.x;
    const int total = NN * DD / 4;
    if (idx >= total) return;
    int c0 = (idx & 15) * 4;
    float4 v = ((const float4*)H)[idx];
    float inv = 1.0f / (float)NN;
    float4 o;
    {
        float mu = stats[c0 + 0] * inv;
        float var = stats[64 + c0 + 0] * inv - mu * mu;
        float sc = gamma[c0 + 0] * rsqrtf(var + BN_EPS);
        float r = sc * (v.x - mu) + beta[c0 + 0];
        o.x = r > 0.f ? r : 0.f;
    }
    {
        float mu = stats[c0 + 1] * inv;
        float var = stats[64 + c0 + 1] * inv - mu * mu;
        float sc = gamma[c0 + 1] * rsqrtf(var + BN_EPS);
        float r = sc * (v.y - mu) + beta[c0 + 1];
        o.y = r > 0.f ? r : 0.f;
    }
    {
        float mu = stats[c0 + 2] * inv;
        float var = stats[64 + c0 + 2] * inv - mu * mu;
        float sc = gamma[c0 + 2] * rsqrtf(var + BN_EPS);
        float r = sc * (v.z - mu) + beta[c0 + 2];
        o.z = r > 0.f ? r : 0.f;
    }
    {
        float mu = stats[c0 + 3] * inv;
        float var = stats[64 + c0 + 3] * inv - mu * mu;
        float sc = gamma[c0 + 3] * rsqrtf(var + BN_EPS);
        float r = sc * (v.w - mu) + beta[c0 + 3];
        o.w = r > 0.f ? r : 0.f;
    }
    ushort4 ob;
    ob.x = f32_to_bf16(o.x); ob.y = f32_to_bf16(o.y);
    ob.z = f32_to_bf16(o.z); ob.w = f32_to_bf16(o.w);
    ((ushort4*)Hb)[idx] = ob;
}

// ---------------- launch ----------------

static inline size_t alignup(size_t x) { return (x + 255) & ~(size_t)255; }

extern "C" void kernel_launch(void* const* d_in, const int* in_sizes, int n_in,
                              void* d_out, int out_size, void* d_ws, size_t ws_size,
                              hipStream_t stream) {
    const float* x      = (const float*)d_in[0];
    const int*   eidx   = (const int*)d_in[1];
    const int*   etype  = (const int*)d_in[2];
    const float* w1     = (const float*)d_in[3];
    const float* root1  = (const float*)d_in[4];
    const float* b1     = (const float*)d_in[5];
    const float* gamma1 = (const float*)d_in[6];
    const float* beta1  = (const float*)d_in[7];
    const float* w2     = (const float*)d_in[8];
    const float* root2  = (const float*)d_in[9];
    const float* b2     = (const float*)d_in[10];
    float* out = (float*)d_out;

    const int* src = eidx;
    const int* dst = eidx + EE;

    char* w = (char*)d_ws;
    int* rowptr = (int*)w;            w += alignup((size_t)(MM + 1) * 4);
    int* btot   = (int*)w;            w += alignup(512 * 4);
    int* bbase  = (int*)w;            w += alignup(512 * 4);
    int* gcur   = (int*)w;            w += alignup(512 * 4);
    int* rec    = (int*)w;            w += alignup((size_t)EE * 4);
    unsigned short* mean = (unsigned short*)w; w += alignup((size_t)NN * 512 * 2);
    float* h    = (float*)w;          w += alignup((size_t)NN * DD * 4);
    unsigned short* xhb = (unsigned short*)w; w += alignup((size_t)NN * DD * 2);
    unsigned short* wct1 = (unsigned short*)w; w += alignup((size_t)64 * KTOT * 2);
    unsigned short* wct2 = (unsigned short*)w; w += alignup((size_t)64 * KTOT * 2);
    float* stats = (float*)w;         w += alignup(128 * 4);
    unsigned int* ebuf = (unsigned int*)mean;   // alias: dead before k_agg writes mean

    hipMemsetAsync(btot, 0, 512 * 4, stream);
    hipMemsetAsync(stats, 0, 128 * 4, stream);

    k_prepw<<<dim3(144), dim3(256), 0, stream>>>(w1, root1, wct1);
    k_prepw<<<dim3(144), dim3(256), 0, stream>>>(w2, root2, wct2);
    k_tobf16<<<dim3(NN * DD / 4 / 256 + 1), dim3(256), 0, stream>>>(x, xhb);

    // bucketed CSR build
    k_bcount<<<dim3(NBIN), dim3(256), 0, stream>>>(dst, btot);
    k_bscan<<<dim3(1), dim3(512), 0, stream>>>(btot, bbase, gcur, rowptr);
    k_bin<<<dim3(NBIN), dim3(256), 0, stream>>>(src, dst, etype, gcur, ebuf);
    k_bcsr<<<dim3(NB), dim3(256), 0, stream>>>(bbase, ebuf, rowptr, rec);

    // layer 1 (gemm fuses BN column stats)
    k_agg<<<dim3((NN + 3) / 4), dim3(256), 0, stream>>>(xhb, rowptr, rec, mean);
    k_gemm<<<dim3((NN + 63) / 64), dim3(256), 0, stream>>>(mean, xhb, wct1, b1, h, stats, 1);
    k_bnrelu<<<dim3(NN * DD / 4 / 256), dim3(256), 0, stream>>>(h, xhb, stats, gamma1, beta1);

    // layer 2 (xhb now holds bf16 of post-BN/ReLU h)
    k_agg<<<dim3((NN + 3) / 4), dim3(256), 0, stream>>>(xhb, rowptr, rec, mean);
    k_gemm<<<dim3((NN + 63) / 64), dim3(256), 0, stream>>>(mean, xhb, wct2, b2, out, stats, 0);
}

// Round 7
// 425.827 us; speedup vs baseline: 1.1261x; 1.0743x over previous
//
#include <hip/hip_runtime.h>
#include <hip/hip_bf16.h>

#define NN 100000
#define EE 1600000
#define RR 8
#define DD 64
#define MM (NN * RR)                 // 800000 (dst,rel) segments
#define BN_EPS 1e-5f
#define KTOT 576                     // 512 (rel) + 64 (root)
#define BSTRIDE 584                  // LDS A row pitch in shorts (292 words % 32 = 4 -> 2-way only)

// bucket sort params: 256 dsts per bucket -> 2048 (dst,rel) keys per bucket
#define NB 391                       // ceil(100000/256)
#define EPB 8192                     // edges per block in binning kernels
#define NBIN ((EE + EPB - 1) / EPB)  // 196

typedef __bf16 bf16x8 __attribute__((ext_vector_type(8)));
typedef float  f32x4  __attribute__((ext_vector_type(4)));

static __device__ __forceinline__ unsigned short f32_to_bf16(float f) {
    unsigned int u = __float_as_uint(f);
    unsigned int r = u + 0x7FFFu + ((u >> 16) & 1u);   // RNE
    return (unsigned short)(r >> 16);
}
static __device__ __forceinline__ float bflo(unsigned int u) {
    return __uint_as_float(u << 16);
}
static __device__ __forceinline__ float bfhi(unsigned int u) {
    return __uint_as_float(u & 0xFFFF0000u);
}

// ---------------- bucketed CSR build ----------------

__global__ void k_bcount(const int* __restrict__ dst, int* __restrict__ btot) {
    __shared__ int cnt[NB];
    int t = threadIdx.x;
    for (int i = t; i < NB; i += 256) cnt[i] = 0;
    __syncthreads();
    int base = blockIdx.x * EPB;
#pragma unroll
    for (int i = 0; i < EPB / 256; ++i) {
        int e = base + i * 256 + t;
        if (e < EE) atomicAdd(&cnt[dst[e] >> 8], 1);
    }
    __syncthreads();
    for (int i = t; i < NB; i += 256)
        if (cnt[i]) atomicAdd(&btot[i], cnt[i]);
}

__global__ void k_bscan(const int* __restrict__ btot, int* __restrict__ bbase,
                        int* __restrict__ gcur, int* __restrict__ rowptr) {
    __shared__ int sd[512];
    int t = threadIdx.x;
    int v = (t < NB) ? btot[t] : 0;
    sd[t] = v;
    __syncthreads();
    for (int off = 1; off < 512; off <<= 1) {
        int x = (t >= off) ? sd[t - off] : 0;
        __syncthreads();
        sd[t] += x;
        __syncthreads();
    }
    if (t < NB) { bbase[t] = sd[t] - v; gcur[t] = sd[t] - v; }
    if (t == NB - 1) { bbase[NB] = sd[t]; rowptr[MM] = sd[t]; }
}

// bin edges into bucket-contiguous ebuf, packed: src | (localkey << 17)
__global__ void k_bin(const int* __restrict__ src, const int* __restrict__ dst,
                      const int* __restrict__ et, int* __restrict__ gcur,
                      unsigned int* __restrict__ ebuf) {
    __shared__ int cnt[NB];
    __shared__ int bas[NB];
    __shared__ int off[NB];
    int t = threadIdx.x;
    for (int i = t; i < NB; i += 256) { cnt[i] = 0; off[i] = 0; }
    __syncthreads();
    int base = blockIdx.x * EPB;
#pragma unroll
    for (int i = 0; i < EPB / 256; ++i) {
        int e = base + i * 256 + t;
        if (e < EE) atomicAdd(&cnt[dst[e] >> 8], 1);
    }
    __syncthreads();
    for (int i = t; i < NB; i += 256) {
        int c = cnt[i];
        bas[i] = c ? atomicAdd(&gcur[i], c) : 0;
    }
    __syncthreads();
#pragma unroll
    for (int i = 0; i < EPB / 256; ++i) {
        int e = base + i * 256 + t;
        if (e < EE) {
            int d = dst[e];
            int b = d >> 8;
            int lk = ((d & 255) << 3) | et[e];
            unsigned int rec0 = (unsigned int)src[e] | ((unsigned int)lk << 17);
            int p = bas[b] + atomicAdd(&off[b], 1);
            ebuf[p] = rec0;
        }
    }
}

// per-bucket: LDS histogram + scan -> rowptr; LDS cursors -> sorted rec
__global__ __launch_bounds__(256) void k_bcsr(const int* __restrict__ bbase,
                                              const unsigned int* __restrict__ ebuf,
                                              int* __restrict__ rowptr,
                                              int* __restrict__ rec) {
    __shared__ int deg[2048];
    __shared__ int part[256];
    int b = blockIdx.x, t = threadIdx.x;
    int e0 = bbase[b], e1 = bbase[b + 1];
    for (int i = t; i < 2048; i += 256) deg[i] = 0;
    __syncthreads();
    for (int e = e0 + t; e < e1; e += 256) atomicAdd(&deg[ebuf[e] >> 17], 1);
    __syncthreads();
    int loc[8];
    int s = 0;
#pragma unroll
    for (int j = 0; j < 8; ++j) { loc[j] = deg[t * 8 + j]; s += loc[j]; }
    part[t] = s;
    __syncthreads();
    for (int off = 1; off < 256; off <<= 1) {
        int x = (t >= off) ? part[t - off] : 0;
        __syncthreads();
        part[t] += x;
        __syncthreads();
    }
    int run = part[t] - s;
    int keyBase = b * 2048;
#pragma unroll
    for (int j = 0; j < 8; ++j) {
        int g = keyBase + t * 8 + j;
        if (g < MM) rowptr[g] = e0 + run;
        deg[t * 8 + j] = run;
        run += loc[j];
    }
    __syncthreads();
    for (int e = e0 + t; e < e1; e += 256) {
        unsigned int v = ebuf[e];
        int lk = v >> 17;
        int pos = e0 + atomicAdd(&deg[lk], 1);
        rec[pos] = (int)(v & 0x1FFFFu);
    }
}

// ---------------- fp32 -> bf16 row conversion ----------------

__global__ void k_tobf16(const float* __restrict__ X, unsigned short* __restrict__ Xb) {
    int i = blockIdx.x * 256 + threadIdx.x;
    if (i >= NN * DD / 4) return;
    float4 v = ((const float4*)X)[i];
    ushort4 o;
    o.x = f32_to_bf16(v.x); o.y = f32_to_bf16(v.y);
    o.z = f32_to_bf16(v.z); o.w = f32_to_bf16(v.w);
    ((ushort4*)Xb)[i] = o;
}

// ---------------- aggregation: wave per dst, 8 lanes per segment ----------------
// mean layout: [N][512] bf16, k = r*64 + d. Edge loop unrolled x4 so the
// rec->Xb dependent chains of consecutive edges overlap.
// (verbatim round-0 kernel: 64.7 us, ~3 TB/s, VGPR 40)

__global__ void k_agg(const unsigned short* __restrict__ Xb,
                      const int* __restrict__ rowptr,
                      const int* __restrict__ rec,
                      unsigned short* __restrict__ mean) {
    int wv = threadIdx.x >> 6;
    int lane = threadIdx.x & 63;
    int n = blockIdx.x * 4 + wv;
    if (n >= NN) return;
    int r = lane >> 3;       // segment 0..7
    int q = lane & 7;        // dim-octet 0..7
    int e0 = rowptr[n * RR + r];
    int e1 = rowptr[n * RR + r + 1];
    float a0[8] = {0,0,0,0,0,0,0,0};
    float a1[8] = {0,0,0,0,0,0,0,0};
    float a2[8] = {0,0,0,0,0,0,0,0};
    float a3[8] = {0,0,0,0,0,0,0,0};
    int e = e0;
    for (; e + 3 < e1; e += 4) {
        int s0 = rec[e], s1 = rec[e + 1], s2 = rec[e + 2], s3 = rec[e + 3];
        uint4 u0 = *(const uint4*)(Xb + (size_t)s0 * DD + q * 8);
        uint4 u1 = *(const uint4*)(Xb + (size_t)s1 * DD + q * 8);
        uint4 u2 = *(const uint4*)(Xb + (size_t)s2 * DD + q * 8);
        uint4 u3 = *(const uint4*)(Xb + (size_t)s3 * DD + q * 8);
        a0[0] += bflo(u0.x); a0[1] += bfhi(u0.x); a0[2] += bflo(u0.y); a0[3] += bfhi(u0.y);
        a0[4] += bflo(u0.z); a0[5] += bfhi(u0.z); a0[6] += bflo(u0.w); a0[7] += bfhi(u0.w);
        a1[0] += bflo(u1.x); a1[1] += bfhi(u1.x); a1[2] += bflo(u1.y); a1[3] += bfhi(u1.y);
        a1[4] += bflo(u1.z); a1[5] += bfhi(u1.z); a1[6] += bflo(u1.w); a1[7] += bfhi(u1.w);
        a2[0] += bflo(u2.x); a2[1] += bfhi(u2.x); a2[2] += bflo(u2.y); a2[3] += bfhi(u2.y);
        a2[4] += bflo(u2.z); a2[5] += bfhi(u2.z); a2[6] += bflo(u2.w); a2[7] += bfhi(u2.w);
        a3[0] += bflo(u3.x); a3[1] += bfhi(u3.x); a3[2] += bflo(u3.y); a3[3] += bfhi(u3.y);
        a3[4] += bflo(u3.z); a3[5] += bfhi(u3.z); a3[6] += bflo(u3.w); a3[7] += bfhi(u3.w);
    }
    if (e + 1 < e1) {
        int s0 = rec[e], s1 = rec[e + 1];
        uint4 u0 = *(const uint4*)(Xb + (size_t)s0 * DD + q * 8);
        uint4 u1 = *(const uint4*)(Xb + (size_t)s1 * DD + q * 8);
        a0[0] += bflo(u0.x); a0[1] += bfhi(u0.x); a0[2] += bflo(u0.y); a0[3] += bfhi(u0.y);
        a0[4] += bflo(u0.z); a0[5] += bfhi(u0.z); a0[6] += bflo(u0.w); a0[7] += bfhi(u0.w);
        a1[0] += bflo(u1.x); a1[1] += bfhi(u1.x); a1[2] += bflo(u1.y); a1[3] += bfhi(u1.y);
        a1[4] += bflo(u1.z); a1[5] += bfhi(u1.z); a1[6] += bflo(u1.w); a1[7] += bfhi(u1.w);
        e += 2;
    }
    if (e < e1) {
        int s0 = rec[e];
        uint4 u0 = *(const uint4*)(Xb + (size_t)s0 * DD + q * 8);
        a0[0] += bflo(u0.x); a0[1] += bfhi(u0.x); a0[2] += bflo(u0.y); a0[3] += bfhi(u0.y);
        a0[4] += bflo(u0.z); a0[5] += bfhi(u0.z); a0[6] += bflo(u0.w); a0[7] += bfhi(u0.w);
    }
    int cnt = e1 - e0;
    float inv = 1.0f / (float)(cnt > 1 ? cnt : 1);
    uint4 o;
    o.x = (unsigned)f32_to_bf16((a0[0]+a1[0]+a2[0]+a3[0]) * inv) | ((unsigned)f32_to_bf16((a0[1]+a1[1]+a2[1]+a3[1]) * inv) << 16);
    o.y = (unsigned)f32_to_bf16((a0[2]+a1[2]+a2[2]+a3[2]) * inv) | ((unsigned)f32_to_bf16((a0[3]+a1[3]+a2[3]+a3[3]) * inv) << 16);
    o.z = (unsigned)f32_to_bf16((a0[4]+a1[4]+a2[4]+a3[4]) * inv) | ((unsigned)f32_to_bf16((a0[5]+a1[5]+a2[5]+a3[5]) * inv) << 16);
    o.w = (unsigned)f32_to_bf16((a0[6]+a1[6]+a2[6]+a3[6]) * inv) | ((unsigned)f32_to_bf16((a0[7]+a1[7]+a2[7]+a3[7]) * inv) << 16);
    *(uint4*)(mean + (size_t)n * 512 + r * 64 + q * 8) = o;
}

// ---------------- weight prep: WcT[64][576] bf16, k = r*64+d (+root tail) ----------------

__global__ void k_prepw(const float* __restrict__ W, const float* __restrict__ Root,
                        unsigned short* __restrict__ WcT) {
    int i = blockIdx.x * 256 + threadIdx.x;
    if (i >= 64 * KTOT) return;
    int o = i / KTOT;
    int k = i - o * KTOT;
    float v;
    if (k < 512) v = W[(size_t)(k >> 6) * 4096 + (k & 63) * 64 + o];
    else         v = Root[(k - 512) * 64 + o];
    WcT[(size_t)o * KTOT + k] = f32_to_bf16(v);
}

// ---------------- MFMA GEMM: out[N][64] = [mean | Xb] @ Wc + bias ----------------
// A (the 100 MB stream) staged cooperatively into padded LDS: coalesced
// uint4 loads + ds_writes, all independent -> HBM latency hidden by the load
// queue. B (L2-hot WcT) kept per-wave in 72 VGPRs (16-col slice, loaded
// once). 73 KB LDS -> 2 blocks/CU so one block stages while the other
// computes. BSTRIDE=584 -> 2-way bank aliasing only (free).
// Tail staging: 64 rows x 8 chunks = 512 chunks = 2 passes of 256 (R6 bug
// was 1 pass of 4 chunks/row -> cols 544..575 uninitialized -> NaN).
// BN stats: columns disjoint per wave -> shfl + atomicAdd, no extra sync.

__global__ __launch_bounds__(256, 2) void k_gemm(const unsigned short* __restrict__ meanB,
                                                 const unsigned short* __restrict__ Xb,
                                                 const unsigned short* __restrict__ WcT,
                                                 const float* __restrict__ bias,
                                                 float* __restrict__ Out,
                                                 float* __restrict__ stats,
                                                 int dostats) {
    __shared__ unsigned short Atile[64 * BSTRIDE];   // 73 KB
    int t = threadIdx.x;
    int wv = t >> 6, lane = t & 63;
    int quad = lane >> 4, m16 = lane & 15;
    int col = wv * 16 + m16;                 // this wave's column slice
    int row0 = blockIdx.x * 64;
    union AU { uint4 u; bf16x8 f; };

    // B once per wave: 18 uint4 = 72 VGPRs (L2-resident WcT)
    AU bfrag[18];
    const unsigned short* bg = WcT + (size_t)col * KTOT + quad * 8;
#pragma unroll
    for (int kb = 0; kb < 18; ++kb)
        bfrag[kb].u = *(const uint4*)(bg + kb * 32);

    // stage A: mean rows (64 rows x 64 uint4 chunks)
#pragma unroll
    for (int i = 0; i < 16; ++i) {
        int c = i * 256 + t;
        int row = c >> 6, k16 = c & 63;
        int grow = row0 + row;
        uint4 v = (grow < NN) ? *(const uint4*)(meanB + (size_t)grow * 512 + k16 * 8)
                              : make_uint4(0, 0, 0, 0);
        *(uint4*)(Atile + row * BSTRIDE + k16 * 8) = v;
    }
    // stage Xb tail (64 rows x 8 uint4 chunks = 512 chunks, 2 passes)
#pragma unroll
    for (int j = 0; j < 2; ++j) {
        int c = j * 256 + t;
        int row = c >> 3, k16 = c & 7;
        int grow = row0 + row;
        uint4 v = (grow < NN) ? *(const uint4*)(Xb + (size_t)grow * 64 + k16 * 8)
                              : make_uint4(0, 0, 0, 0);
        *(uint4*)(Atile + row * BSTRIDE + 512 + k16 * 8) = v;
    }
    __syncthreads();

    float bb = bias[col];
    float s = 0.f, sq = 0.f;
    f32x4 accs[4];

#pragma unroll
    for (int rt = 0; rt < 4; ++rt) {
        const unsigned short* as = Atile + (rt * 16 + m16) * BSTRIDE + quad * 8;
        f32x4 a = (f32x4){0.f, 0.f, 0.f, 0.f};
#pragma unroll
        for (int kb = 0; kb < 18; ++kb) {
            AU av;
            av.u = *(const uint4*)(as + kb * 32);
            a = __builtin_amdgcn_mfma_f32_16x16x32_bf16(av.f, bfrag[kb].f, a, 0, 0, 0);
        }
        accs[rt] = a;
    }

    // epilogue: store + stats (per-lane, columns disjoint across waves)
#pragma unroll
    for (int rt = 0; rt < 4; ++rt) {
#pragma unroll
        for (int i = 0; i < 4; ++i) {
            int row = row0 + rt * 16 + quad * 4 + i;
            if (row < NN) {
                float v = accs[rt][i] + bb;
                Out[(size_t)row * 64 + col] = v;
                s += v; sq += v * v;
            }
        }
    }
    if (dostats) {
        s += __shfl_xor(s, 16); s += __shfl_xor(s, 32);
        sq += __shfl_xor(sq, 16); sq += __shfl_xor(sq, 32);
        if (quad == 0) {
            atomicAdd(&stats[col], s);
            atomicAdd(&stats[64 + col], sq);
        }
    }
}

// ---------------- BN+ReLU (read fp32 H, write bf16 Hb only) ----------------

__global__ void k_bnrelu(const float* __restrict__ H, unsigned short* __restrict__ Hb,
                         const float* __restrict__ stats,
                         const float* __restrict__ gamma, const float* __restrict__ beta) {
    int idx = blockIdx.x * 256 + threadIdx.x;
    const int total = NN * DD / 4;
    if (idx >= total) return;
    int c0 = (idx & 15) * 4;
    float4 v = ((const float4*)H)[idx];
    float inv = 1.0f / (float)NN;
    float4 o;
    {
        float mu = stats[c0 + 0] * inv;
        float var = stats[64 + c0 + 0] * inv - mu * mu;
        float sc = gamma[c0 + 0] * rsqrtf(var + BN_EPS);
        float r = sc * (v.x - mu) + beta[c0 + 0];
        o.x = r > 0.f ? r : 0.f;
    }
    {
        float mu = stats[c0 + 1] * inv;
        float var = stats[64 + c0 + 1] * inv - mu * mu;
        float sc = gamma[c0 + 1] * rsqrtf(var + BN_EPS);
        float r = sc * (v.y - mu) + beta[c0 + 1];
        o.y = r > 0.f ? r : 0.f;
    }
    {
        float mu = stats[c0 + 2] * inv;
        float var = stats[64 + c0 + 2] * inv - mu * mu;
        float sc = gamma[c0 + 2] * rsqrtf(var + BN_EPS);
        float r = sc * (v.z - mu) + beta[c0 + 2];
        o.z = r > 0.f ? r : 0.f;
    }
    {
        float mu = stats[c0 + 3] * inv;
        float var = stats[64 + c0 + 3] * inv - mu * mu;
        float sc = gamma[c0 + 3] * rsqrtf(var + BN_EPS);
        float r = sc * (v.w - mu) + beta[c0 + 3];
        o.w = r > 0.f ? r : 0.f;
    }
    ushort4 ob;
    ob.x = f32_to_bf16(o.x); ob.y = f32_to_bf16(o.y);
    ob.z = f32_to_bf16(o.z); ob.w = f32_to_bf16(o.w);
    ((ushort4*)Hb)[idx] = ob;
}

// ---------------- launch ----------------

static inline size_t alignup(size_t x) { return (x + 255) & ~(size_t)255; }

extern "C" void kernel_launch(void* const* d_in, const int* in_sizes, int n_in,
                              void* d_out, int out_size, void* d_ws, size_t ws_size,
                              hipStream_t stream) {
    const float* x      = (const float*)d_in[0];
    const int*   eidx   = (const int*)d_in[1];
    const int*   etype  = (const int*)d_in[2];
    const float* w1     = (const float*)d_in[3];
    const float* root1  = (const float*)d_in[4];
    const float* b1     = (const float*)d_in[5];
    const float* gamma1 = (const float*)d_in[6];
    const float* beta1  = (const float*)d_in[7];
    const float* w2     = (const float*)d_in[8];
    const float* root2  = (const float*)d_in[9];
    const float* b2     = (const float*)d_in[10];
    float* out = (float*)d_out;

    const int* src = eidx;
    const int* dst = eidx + EE;

    char* w = (char*)d_ws;
    int* rowptr = (int*)w;            w += alignup((size_t)(MM + 1) * 4);
    int* btot   = (int*)w;            w += alignup(512 * 4);
    int* bbase  = (int*)w;            w += alignup(512 * 4);
    int* gcur   = (int*)w;            w += alignup(512 * 4);
    int* rec    = (int*)w;            w += alignup((size_t)EE * 4);
    unsigned short* mean = (unsigned short*)w; w += alignup((size_t)NN * 512 * 2);
    float* h    = (float*)w;          w += alignup((size_t)NN * DD * 4);
    unsigned short* xhb = (unsigned short*)w; w += alignup((size_t)NN * DD * 2);
    unsigned short* wct1 = (unsigned short*)w; w += alignup((size_t)64 * KTOT * 2);
    unsigned short* wct2 = (unsigned short*)w; w += alignup((size_t)64 * KTOT * 2);
    float* stats = (float*)w;         w += alignup(128 * 4);
    unsigned int* ebuf = (unsigned int*)mean;   // alias: dead before k_agg writes mean

    hipMemsetAsync(btot, 0, 512 * 4, stream);
    hipMemsetAsync(stats, 0, 128 * 4, stream);

    k_prepw<<<dim3(144), dim3(256), 0, stream>>>(w1, root1, wct1);
    k_prepw<<<dim3(144), dim3(256), 0, stream>>>(w2, root2, wct2);
    k_tobf16<<<dim3(NN * DD / 4 / 256 + 1), dim3(256), 0, stream>>>(x, xhb);

    // bucketed CSR build
    k_bcount<<<dim3(NBIN), dim3(256), 0, stream>>>(dst, btot);
    k_bscan<<<dim3(1), dim3(512), 0, stream>>>(btot, bbase, gcur, rowptr);
    k_bin<<<dim3(NBIN), dim3(256), 0, stream>>>(src, dst, etype, gcur, ebuf);
    k_bcsr<<<dim3(NB), dim3(256), 0, stream>>>(bbase, ebuf, rowptr, rec);

    // layer 1 (gemm fuses BN column stats)
    k_agg<<<dim3((NN + 3) / 4), dim3(256), 0, stream>>>(xhb, rowptr, rec, mean);
    k_gemm<<<dim3((NN + 63) / 64), dim3(256), 0, stream>>>(mean, xhb, wct1, b1, h, stats, 1);
    k_bnrelu<<<dim3(NN * DD / 4 / 256), dim3(256), 0, stream>>>(h, xhb, stats, gamma1, beta1);

    // layer 2 (xhb now holds bf16 of post-BN/ReLU h)
    k_agg<<<dim3((NN + 3) / 4), dim3(256), 0, stream>>>(xhb, rowptr, rec, mean);
    k_gemm<<<dim3((NN + 63) / 64), dim3(256), 0, stream>>>(mean, xhb, wct2, b2, out, stats, 0);
}

// Round 8
// 424.408 us; speedup vs baseline: 1.1298x; 1.0033x over previous
//
#include <hip/hip_runtime.h>
#include <hip/hip_bf16.h>

#define NN 100000
#define EE 1600000
#define RR 8
#define DD 64
#define MM (NN * RR)                 // 800000 (dst,rel) segments
#define BN_EPS 1e-5f
#define KTOT 576                     // 512 (rel) + 64 (root)
#define BSTRIDE 584                  // LDS A row pitch in shorts (292 words % 32 = 4)
#define GROWS 32                     // rows per k_gemm block (NN = 32 * 3125 exactly)

// bucket sort params: 256 dsts per bucket -> 2048 (dst,rel) keys per bucket
#define NB 391                       // ceil(100000/256)
#define EPB 8192                     // edges per block in binning kernels
#define NBIN ((EE + EPB - 1) / EPB)  // 196

typedef __bf16 bf16x8 __attribute__((ext_vector_type(8)));
typedef float  f32x4  __attribute__((ext_vector_type(4)));

static __device__ __forceinline__ unsigned short f32_to_bf16(float f) {
    unsigned int u = __float_as_uint(f);
    unsigned int r = u + 0x7FFFu + ((u >> 16) & 1u);   // RNE
    return (unsigned short)(r >> 16);
}
static __device__ __forceinline__ float bflo(unsigned int u) {
    return __uint_as_float(u << 16);
}
static __device__ __forceinline__ float bfhi(unsigned int u) {
    return __uint_as_float(u & 0xFFFF0000u);
}

// direct global->LDS copy, 16 B per lane; LDS dst = wave-uniform base + lane*16
static __device__ __forceinline__ void gload_lds16(const unsigned short* g, unsigned short* l) {
    __builtin_amdgcn_global_load_lds(
        (const __attribute__((address_space(1))) unsigned int*)(const void*)g,
        (__attribute__((address_space(3))) unsigned int*)(void*)l,
        16, 0, 0);
}

// ---------------- bucketed CSR build ----------------

__global__ void k_bcount(const int* __restrict__ dst, int* __restrict__ btot) {
    __shared__ int cnt[NB];
    int t = threadIdx.x;
    for (int i = t; i < NB; i += 256) cnt[i] = 0;
    __syncthreads();
    int base = blockIdx.x * EPB;
#pragma unroll
    for (int i = 0; i < EPB / 256; ++i) {
        int e = base + i * 256 + t;
        if (e < EE) atomicAdd(&cnt[dst[e] >> 8], 1);
    }
    __syncthreads();
    for (int i = t; i < NB; i += 256)
        if (cnt[i]) atomicAdd(&btot[i], cnt[i]);
}

__global__ void k_bscan(const int* __restrict__ btot, int* __restrict__ bbase,
                        int* __restrict__ gcur, int* __restrict__ rowptr) {
    __shared__ int sd[512];
    int t = threadIdx.x;
    int v = (t < NB) ? btot[t] : 0;
    sd[t] = v;
    __syncthreads();
    for (int off = 1; off < 512; off <<= 1) {
        int x = (t >= off) ? sd[t - off] : 0;
        __syncthreads();
        sd[t] += x;
        __syncthreads();
    }
    if (t < NB) { bbase[t] = sd[t] - v; gcur[t] = sd[t] - v; }
    if (t == NB - 1) { bbase[NB] = sd[t]; rowptr[MM] = sd[t]; }
}

// bin edges into bucket-contiguous ebuf, packed: src | (localkey << 17)
__global__ void k_bin(const int* __restrict__ src, const int* __restrict__ dst,
                      const int* __restrict__ et, int* __restrict__ gcur,
                      unsigned int* __restrict__ ebuf) {
    __shared__ int cnt[NB];
    __shared__ int bas[NB];
    __shared__ int off[NB];
    int t = threadIdx.x;
    for (int i = t; i < NB; i += 256) { cnt[i] = 0; off[i] = 0; }
    __syncthreads();
    int base = blockIdx.x * EPB;
#pragma unroll
    for (int i = 0; i < EPB / 256; ++i) {
        int e = base + i * 256 + t;
        if (e < EE) atomicAdd(&cnt[dst[e] >> 8], 1);
    }
    __syncthreads();
    for (int i = t; i < NB; i += 256) {
        int c = cnt[i];
        bas[i] = c ? atomicAdd(&gcur[i], c) : 0;
    }
    __syncthreads();
#pragma unroll
    for (int i = 0; i < EPB / 256; ++i) {
        int e = base + i * 256 + t;
        if (e < EE) {
            int d = dst[e];
            int b = d >> 8;
            int lk = ((d & 255) << 3) | et[e];
            unsigned int rec0 = (unsigned int)src[e] | ((unsigned int)lk << 17);
            int p = bas[b] + atomicAdd(&off[b], 1);
            ebuf[p] = rec0;
        }
    }
}

// per-bucket: LDS histogram + scan -> rowptr; LDS cursors -> sorted rec
__global__ __launch_bounds__(256) void k_bcsr(const int* __restrict__ bbase,
                                              const unsigned int* __restrict__ ebuf,
                                              int* __restrict__ rowptr,
                                              int* __restrict__ rec) {
    __shared__ int deg[2048];
    __shared__ int part[256];
    int b = blockIdx.x, t = threadIdx.x;
    int e0 = bbase[b], e1 = bbase[b + 1];
    for (int i = t; i < 2048; i += 256) deg[i] = 0;
    __syncthreads();
    for (int e = e0 + t; e < e1; e += 256) atomicAdd(&deg[ebuf[e] >> 17], 1);
    __syncthreads();
    int loc[8];
    int s = 0;
#pragma unroll
    for (int j = 0; j < 8; ++j) { loc[j] = deg[t * 8 + j]; s += loc[j]; }
    part[t] = s;
    __syncthreads();
    for (int off = 1; off < 256; off <<= 1) {
        int x = (t >= off) ? part[t - off] : 0;
        __syncthreads();
        part[t] += x;
        __syncthreads();
    }
    int run = part[t] - s;
    int keyBase = b * 2048;
#pragma unroll
    for (int j = 0; j < 8; ++j) {
        int g = keyBase + t * 8 + j;
        if (g < MM) rowptr[g] = e0 + run;
        deg[t * 8 + j] = run;
        run += loc[j];
    }
    __syncthreads();
    for (int e = e0 + t; e < e1; e += 256) {
        unsigned int v = ebuf[e];
        int lk = v >> 17;
        int pos = e0 + atomicAdd(&deg[lk], 1);
        rec[pos] = (int)(v & 0x1FFFFu);
    }
}

// ---------------- fp32 -> bf16 row conversion ----------------

__global__ void k_tobf16(const float* __restrict__ X, unsigned short* __restrict__ Xb) {
    int i = blockIdx.x * 256 + threadIdx.x;
    if (i >= NN * DD / 4) return;
    float4 v = ((const float4*)X)[i];
    ushort4 o;
    o.x = f32_to_bf16(v.x); o.y = f32_to_bf16(v.y);
    o.z = f32_to_bf16(v.z); o.w = f32_to_bf16(v.w);
    ((ushort4*)Xb)[i] = o;
}

// ---------------- aggregation: wave per dst, 8 lanes per segment ----------------
// (verbatim round-0 kernel: 64.7 us, ~3 TB/s, VGPR 40)

__global__ void k_agg(const unsigned short* __restrict__ Xb,
                      const int* __restrict__ rowptr,
                      const int* __restrict__ rec,
                      unsigned short* __restrict__ mean) {
    int wv = threadIdx.x >> 6;
    int lane = threadIdx.x & 63;
    int n = blockIdx.x * 4 + wv;
    if (n >= NN) return;
    int r = lane >> 3;       // segment 0..7
    int q = lane & 7;        // dim-octet 0..7
    int e0 = rowptr[n * RR + r];
    int e1 = rowptr[n * RR + r + 1];
    float a0[8] = {0,0,0,0,0,0,0,0};
    float a1[8] = {0,0,0,0,0,0,0,0};
    float a2[8] = {0,0,0,0,0,0,0,0};
    float a3[8] = {0,0,0,0,0,0,0,0};
    int e = e0;
    for (; e + 3 < e1; e += 4) {
        int s0 = rec[e], s1 = rec[e + 1], s2 = rec[e + 2], s3 = rec[e + 3];
        uint4 u0 = *(const uint4*)(Xb + (size_t)s0 * DD + q * 8);
        uint4 u1 = *(const uint4*)(Xb + (size_t)s1 * DD + q * 8);
        uint4 u2 = *(const uint4*)(Xb + (size_t)s2 * DD + q * 8);
        uint4 u3 = *(const uint4*)(Xb + (size_t)s3 * DD + q * 8);
        a0[0] += bflo(u0.x); a0[1] += bfhi(u0.x); a0[2] += bflo(u0.y); a0[3] += bfhi(u0.y);
        a0[4] += bflo(u0.z); a0[5] += bfhi(u0.z); a0[6] += bflo(u0.w); a0[7] += bfhi(u0.w);
        a1[0] += bflo(u1.x); a1[1] += bfhi(u1.x); a1[2] += bflo(u1.y); a1[3] += bfhi(u1.y);
        a1[4] += bflo(u1.z); a1[5] += bfhi(u1.z); a1[6] += bflo(u1.w); a1[7] += bfhi(u1.w);
        a2[0] += bflo(u2.x); a2[1] += bfhi(u2.x); a2[2] += bflo(u2.y); a2[3] += bfhi(u2.y);
        a2[4] += bflo(u2.z); a2[5] += bfhi(u2.z); a2[6] += bflo(u2.w); a2[7] += bfhi(u2.w);
        a3[0] += bflo(u3.x); a3[1] += bfhi(u3.x); a3[2] += bflo(u3.y); a3[3] += bfhi(u3.y);
        a3[4] += bflo(u3.z); a3[5] += bfhi(u3.z); a3[6] += bflo(u3.w); a3[7] += bfhi(u3.w);
    }
    if (e + 1 < e1) {
        int s0 = rec[e], s1 = rec[e + 1];
        uint4 u0 = *(const uint4*)(Xb + (size_t)s0 * DD + q * 8);
        uint4 u1 = *(const uint4*)(Xb + (size_t)s1 * DD + q * 8);
        a0[0] += bflo(u0.x); a0[1] += bfhi(u0.x); a0[2] += bflo(u0.y); a0[3] += bfhi(u0.y);
        a0[4] += bflo(u0.z); a0[5] += bfhi(u0.z); a0[6] += bflo(u0.w); a0[7] += bfhi(u0.w);
        a1[0] += bflo(u1.x); a1[1] += bfhi(u1.x); a1[2] += bflo(u1.y); a1[3] += bfhi(u1.y);
        a1[4] += bflo(u1.z); a1[5] += bfhi(u1.z); a1[6] += bflo(u1.w); a1[7] += bfhi(u1.w);
        e += 2;
    }
    if (e < e1) {
        int s0 = rec[e];
        uint4 u0 = *(const uint4*)(Xb + (size_t)s0 * DD + q * 8);
        a0[0] += bflo(u0.x); a0[1] += bfhi(u0.x); a0[2] += bflo(u0.y); a0[3] += bfhi(u0.y);
        a0[4] += bflo(u0.z); a0[5] += bfhi(u0.z); a0[6] += bflo(u0.w); a0[7] += bfhi(u0.w);
    }
    int cnt = e1 - e0;
    float inv = 1.0f / (float)(cnt > 1 ? cnt : 1);
    uint4 o;
    o.x = (unsigned)f32_to_bf16((a0[0]+a1[0]+a2[0]+a3[0]) * inv) | ((unsigned)f32_to_bf16((a0[1]+a1[1]+a2[1]+a3[1]) * inv) << 16);
    o.y = (unsigned)f32_to_bf16((a0[2]+a1[2]+a2[2]+a3[2]) * inv) | ((unsigned)f32_to_bf16((a0[3]+a1[3]+a2[3]+a3[3]) * inv) << 16);
    o.z = (unsigned)f32_to_bf16((a0[4]+a1[4]+a2[4]+a3[4]) * inv) | ((unsigned)f32_to_bf16((a0[5]+a1[5]+a2[5]+a3[5]) * inv) << 16);
    o.w = (unsigned)f32_to_bf16((a0[6]+a1[6]+a2[6]+a3[6]) * inv) | ((unsigned)f32_to_bf16((a0[7]+a1[7]+a2[7]+a3[7]) * inv) << 16);
    *(uint4*)(mean + (size_t)n * 512 + r * 64 + q * 8) = o;
}

// ---------------- weight prep: WcT[64][576] bf16, k = r*64+d (+root tail) ----------------

__global__ void k_prepw(const float* __restrict__ W, const float* __restrict__ Root,
                        unsigned short* __restrict__ WcT) {
    int i = blockIdx.x * 256 + threadIdx.x;
    if (i >= 64 * KTOT) return;
    int o = i / KTOT;
    int k = i - o * KTOT;
    float v;
    if (k < 512) v = W[(size_t)(k >> 6) * 4096 + (k & 63) * 64 + o];
    else         v = Root[(k - 512) * 64 + o];
    WcT[(size_t)o * KTOT + k] = f32_to_bf16(v);
}

// ---------------- MFMA GEMM: out[N][64] = [mean | Xb] @ Wc + bias ----------------
// 32 rows/block (NN = 32*3125 exactly -> no bounds checks), 4 waves.
// Mean rows staged via global_load_lds width=16: one instruction per row
// (64 lanes x 16 B = 1024 B = one full mean row; per-lane global src,
// wave-uniform LDS row base -> m104 constraint satisfied; the row pad sits
// between rows). No VGPR round-trip -> all staging loads stay in flight.
// Xb tail (32 rows x 128 B = 4 KB) reg-staged in ONE pass (1 load/thread).
// B per wave in 72 VGPRs (L2-resident WcT). LDS 37.4 KB -> 4 blocks/CU.
// BN stats: columns disjoint per wave -> shfl + atomicAdd.

__global__ __launch_bounds__(256, 4) void k_gemm(const unsigned short* __restrict__ meanB,
                                                 const unsigned short* __restrict__ Xb,
                                                 const unsigned short* __restrict__ WcT,
                                                 const float* __restrict__ bias,
                                                 float* __restrict__ Out,
                                                 float* __restrict__ stats,
                                                 int dostats) {
    __shared__ unsigned short Atile[GROWS * BSTRIDE];   // 37376 B
    int t = threadIdx.x;
    int wv = t >> 6, lane = t & 63;
    int quad = lane >> 4, m16 = lane & 15;
    int col = wv * 16 + m16;                 // this wave's column slice
    int row0 = blockIdx.x * GROWS;
    union AU { uint4 u; bf16x8 f; };

    // stage mean rows: wave wv issues rows wv*8 .. wv*8+7 direct to LDS
#pragma unroll
    for (int i = 0; i < 8; ++i) {
        int r = wv * 8 + i;
        gload_lds16(meanB + (size_t)(row0 + r) * 512 + lane * 8,
                    Atile + r * BSTRIDE);
    }
    // stage Xb tail: thread t -> row t>>3, chunk t&7 (one pass)
    {
        int row = t >> 3, c = t & 7;
        uint4 v = *(const uint4*)(Xb + (size_t)(row0 + row) * 64 + c * 8);
        *(uint4*)(Atile + row * BSTRIDE + 512 + c * 8) = v;
    }

    // B once per wave: 18 uint4 = 72 VGPRs (L2-resident WcT)
    AU bfrag[18];
    const unsigned short* bg = WcT + (size_t)col * KTOT + quad * 8;
#pragma unroll
    for (int kb = 0; kb < 18; ++kb)
        bfrag[kb].u = *(const uint4*)(bg + kb * 32);

    __syncthreads();   // compiler drains vmcnt (incl. global_load_lds) here

    float bb = bias[col];
    float s = 0.f, sq = 0.f;
    f32x4 accs[2];

#pragma unroll
    for (int rt = 0; rt < 2; ++rt) {
        const unsigned short* as = Atile + (rt * 16 + m16) * BSTRIDE + quad * 8;
        f32x4 a = (f32x4){0.f, 0.f, 0.f, 0.f};
#pragma unroll
        for (int kb = 0; kb < 18; ++kb) {
            AU av;
            av.u = *(const uint4*)(as + kb * 32);
            a = __builtin_amdgcn_mfma_f32_16x16x32_bf16(av.f, bfrag[kb].f, a, 0, 0, 0);
        }
        accs[rt] = a;
    }

    // epilogue: store + stats (per-lane, columns disjoint across waves)
#pragma unroll
    for (int rt = 0; rt < 2; ++rt) {
#pragma unroll
        for (int i = 0; i < 4; ++i) {
            int row = row0 + rt * 16 + quad * 4 + i;
            float v = accs[rt][i] + bb;
            Out[(size_t)row * 64 + col] = v;
            s += v; sq += v * v;
        }
    }
    if (dostats) {
        s += __shfl_xor(s, 16); s += __shfl_xor(s, 32);
        sq += __shfl_xor(sq, 16); sq += __shfl_xor(sq, 32);
        if (quad == 0) {
            atomicAdd(&stats[col], s);
            atomicAdd(&stats[64 + col], sq);
        }
    }
}

// ---------------- BN+ReLU (read fp32 H, write bf16 Hb only) ----------------

__global__ void k_bnrelu(const float* __restrict__ H, unsigned short* __restrict__ Hb,
                         const float* __restrict__ stats,
                         const float* __restrict__ gamma, const float* __restrict__ beta) {
    int idx = blockIdx.x * 256 + threadIdx.x;
    const int total = NN * DD / 4;
    if (idx >= total) return;
    int c0 = (idx & 15) * 4;
    float4 v = ((const float4*)H)[idx];
    float inv = 1.0f / (float)NN;
    float4 o;
    {
        float mu = stats[c0 + 0] * inv;
        float var = stats[64 + c0 + 0] * inv - mu * mu;
        float sc = gamma[c0 + 0] * rsqrtf(var + BN_EPS);
        float r = sc * (v.x - mu) + beta[c0 + 0];
        o.x = r > 0.f ? r : 0.f;
    }
    {
        float mu = stats[c0 + 1] * inv;
        float var = stats[64 + c0 + 1] * inv - mu * mu;
        float sc = gamma[c0 + 1] * rsqrtf(var + BN_EPS);
        float r = sc * (v.y - mu) + beta[c0 + 1];
        o.y = r > 0.f ? r : 0.f;
    }
    {
        float mu = stats[c0 + 2] * inv;
        float var = stats[64 + c0 + 2] * inv - mu * mu;
        float sc = gamma[c0 + 2] * rsqrtf(var + BN_EPS);
        float r = sc * (v.z - mu) + beta[c0 + 2];
        o.z = r > 0.f ? r : 0.f;
    }
    {
        float mu = stats[c0 + 3] * inv;
        float var = stats[64 + c0 + 3] * inv - mu * mu;
        float sc = gamma[c0 + 3] * rsqrtf(var + BN_EPS);
        float r = sc * (v.w - mu) + beta[c0 + 3];
        o.w = r > 0.f ? r : 0.f;
    }
    ushort4 ob;
    ob.x = f32_to_bf16(o.x); ob.y = f32_to_bf16(o.y);
    ob.z = f32_to_bf16(o.z); ob.w = f32_to_bf16(o.w);
    ((ushort4*)Hb)[idx] = ob;
}

// ---------------- launch ----------------

static inline size_t alignup(size_t x) { return (x + 255) & ~(size_t)255; }

extern "C" void kernel_launch(void* const* d_in, const int* in_sizes, int n_in,
                              void* d_out, int out_size, void* d_ws, size_t ws_size,
                              hipStream_t stream) {
    const float* x      = (const float*)d_in[0];
    const int*   eidx   = (const int*)d_in[1];
    const int*   etype  = (const int*)d_in[2];
    const float* w1     = (const float*)d_in[3];
    const float* root1  = (const float*)d_in[4];
    const float* b1     = (const float*)d_in[5];
    const float* gamma1 = (const float*)d_in[6];
    const float* beta1  = (const float*)d_in[7];
    const float* w2     = (const float*)d_in[8];
    const float* root2  = (const float*)d_in[9];
    const float* b2     = (const float*)d_in[10];
    float* out = (float*)d_out;

    const int* src = eidx;
    const int* dst = eidx + EE;

    char* w = (char*)d_ws;
    int* rowptr = (int*)w;            w += alignup((size_t)(MM + 1) * 4);
    int* btot   = (int*)w;            w += alignup(512 * 4);
    int* bbase  = (int*)w;            w += alignup(512 * 4);
    int* gcur   = (int*)w;            w += alignup(512 * 4);
    int* rec    = (int*)w;            w += alignup((size_t)EE * 4);
    unsigned short* mean = (unsigned short*)w; w += alignup((size_t)NN * 512 * 2);
    float* h    = (float*)w;          w += alignup((size_t)NN * DD * 4);
    unsigned short* xhb = (unsigned short*)w; w += alignup((size_t)NN * DD * 2);
    unsigned short* wct1 = (unsigned short*)w; w += alignup((size_t)64 * KTOT * 2);
    unsigned short* wct2 = (unsigned short*)w; w += alignup((size_t)64 * KTOT * 2);
    float* stats = (float*)w;         w += alignup(128 * 4);
    unsigned int* ebuf = (unsigned int*)mean;   // alias: dead before k_agg writes mean

    hipMemsetAsync(btot, 0, 512 * 4, stream);
    hipMemsetAsync(stats, 0, 128 * 4, stream);

    k_prepw<<<dim3(144), dim3(256), 0, stream>>>(w1, root1, wct1);
    k_prepw<<<dim3(144), dim3(256), 0, stream>>>(w2, root2, wct2);
    k_tobf16<<<dim3(NN * DD / 4 / 256 + 1), dim3(256), 0, stream>>>(x, xhb);

    // bucketed CSR build
    k_bcount<<<dim3(NBIN), dim3(256), 0, stream>>>(dst, btot);
    k_bscan<<<dim3(1), dim3(512), 0, stream>>>(btot, bbase, gcur, rowptr);
    k_bin<<<dim3(NBIN), dim3(256), 0, stream>>>(src, dst, etype, gcur, ebuf);
    k_bcsr<<<dim3(NB), dim3(256), 0, stream>>>(bbase, ebuf, rowptr, rec);

    // layer 1 (gemm fuses BN column stats)
    k_agg<<<dim3((NN + 3) / 4), dim3(256), 0, stream>>>(xhb, rowptr, rec, mean);
    k_gemm<<<dim3(NN / GROWS), dim3(256), 0, stream>>>(mean, xhb, wct1, b1, h, stats, 1);
    k_bnrelu<<<dim3(NN * DD / 4 / 256), dim3(256), 0, stream>>>(h, xhb, stats, gamma1, beta1);

    // layer 2 (xhb now holds bf16 of post-BN/ReLU h)
    k_agg<<<dim3((NN + 3) / 4), dim3(256), 0, stream>>>(xhb, rowptr, rec, mean);
    k_gemm<<<dim3(NN / GROWS), dim3(256), 0, stream>>>(mean, xhb, wct2, b2, out, stats, 0);
}